// Round 4
// baseline (6213.015 us; speedup 1.0000x reference)
//
#include <hip/hip_runtime.h>
#include <hip/hip_bf16.h>

// DissipativeSimplestRINN: sequential RK4 + fixed-point tanh solves.
// 64 blocks x 256 threads; block = 16 batch rows; 4 waves split the 128 w-columns.
// Round 4: fused stage boundaries (20 barrier-units/step), raw s_barrier with
// lgkm-only drain (globals fly across barriers), ds_bpermute x-transpose (no xlds).

#define T_SZ 1024
#define NY 32
#define NX 16
#define NW 128
#define NU 8
#define DT_F 0.01f
#define NCOLD 30
#define NWARM 5
#define KAPPA 2.8853900817779268f  // 2*log2(e): prescale solve weights so tanh needs no mul

typedef __attribute__((ext_vector_type(8))) short bf8v;   // 8 bf16 (4 VGPR)
typedef __attribute__((ext_vector_type(4))) float f4v;    // MFMA C/D

#define MFMA16(a, b, c) __builtin_amdgcn_mfma_f32_16x16x32_bf16((a), (b), (c), 0, 0, 0)

__device__ __forceinline__ unsigned short f2bf(float f) {
  return __builtin_bit_cast(unsigned short, __float2bfloat16(f));
}
__device__ __forceinline__ float bf2f(unsigned short u) {
  return __bfloat162float(__builtin_bit_cast(__hip_bfloat16, u));
}
__device__ __forceinline__ short tanh_bf(float z) {  // z pre-scaled by KAPPA
  float e = __builtin_amdgcn_exp2f(z);
  float r = __builtin_amdgcn_rcpf(e + 1.0f);
  return (short)f2bf(1.0f - 2.0f * r);
}
// LDS producer-consumer barrier WITHOUT the compiler's vmcnt(0) drain:
// global loads/stores stay in flight across it.
__device__ __forceinline__ void wave_barrier() {
  asm volatile("s_waitcnt lgkmcnt(0)" ::: "memory");
  __builtin_amdgcn_s_barrier();
  asm volatile("" ::: "memory");
}

__global__ __launch_bounds__(256, 1) void rinn_kernel(
    const float* __restrict__ obs, const float* __restrict__ x0,
    const float* __restrict__ A_T, const float* __restrict__ Bw_T,
    const float* __restrict__ By_T, const float* __restrict__ Cv_T,
    const float* __restrict__ Dvw_T, const float* __restrict__ Dvy_T,
    const float* __restrict__ Cu_T, const float* __restrict__ Duw_T,
    const float* __restrict__ Duy_T, const float* __restrict__ log_stds,
    float* __restrict__ out) {
  // w: 2 bufs x [16 rows][128 bf16]; byte = buf*4096 + r*256 + ((2j) ^ ((r&7)<<4))
  __shared__ __align__(16) char wlds[8192];

  const int tid = (int)threadIdx.x;
  const int wv = tid >> 6;
  const int lane = tid & 63;
  const int r = lane & 15;
  const int h = lane >> 4;
  const long grow = (long)(blockIdx.x * 16 + r);
  const int sw = (r & 7) << 4;
  const int rbase = r * 256;

  // LDS 16B-slot offsets per B-frag slot s (slot s holds K-block f=(wv+s)&3).
  const int ro0 = (64 * wv + 16 * h) ^ sw;
  const int ro1 = (64 * ((wv + 1) & 3) + 16 * h) ^ sw;
  const int ro2 = (64 * ((wv + 2) & 3) + 16 * h) ^ sw;
  const int ro3 = (64 * ((wv + 3) & 3) + 16 * h) ^ sw;

  // bpermute byte-indices for x D-layout -> B-frag transpose
  const int ti0 = 4 * (r + 16 * ((2 * h) & 3));
  const int ti1 = 4 * (r + 16 * ((2 * h + 1) & 3));
  const bool hi_sel = (h < 2);

  // ---- constant A-fragments (j-remap: j = 32wv + 8h' + 4gi + i) ----
  bf8v Adw[2][4], Acv[2], Ady[2];
#pragma unroll
  for (int gi = 0; gi < 2; ++gi) {
    const int j = 32 * wv + 8 * (r >> 2) + 4 * gi + (r & 3);
#pragma unroll
    for (int s = 0; s < 4; ++s) {
      const int f = (wv + s) & 3;
#pragma unroll
      for (int q = 0; q < 8; ++q)
        Adw[gi][s][q] = (short)f2bf(KAPPA * Dvw_T[(32 * f + 8 * h + q) * NW + j]);
    }
#pragma unroll
    for (int q = 0; q < 8; ++q) {
      Acv[gi][q] = (short)f2bf(KAPPA * Cv_T[((8 * h + q) & 15) * NW + j]);  // x hi/lo
      Ady[gi][q] = (short)f2bf(KAPPA * Dvy_T[(8 * h + q) * NW + j]);
    }
  }
  // xdot frags (ALL waves, redundant) + u frags (wave1 only)
  bf8v Ax, Akx[4], Ayx, Au, Aku[4], Ayu;
#pragma unroll
  for (int q = 0; q < 8; ++q) {
    int k = 8 * h + q;
    Ax[q] = (short)f2bf(A_T[(k & 15) * NX + r]);
    Ayx[q] = (short)f2bf(By_T[k * NX + r]);
    float cu = 0.f, dy = 0.f;
    if (wv == 1 && r < NU) { cu = Cu_T[(k & 15) * NU + r]; dy = Duy_T[k * NU + r]; }
    Au[q] = (short)f2bf(cu);
    Ayu[q] = (short)f2bf(dy);
  }
#pragma unroll
  for (int s = 0; s < 4; ++s) {
    const int f = (wv + s) & 3;
#pragma unroll
    for (int q = 0; q < 8; ++q) {
      int k = 32 * f + 8 * h + q;
      Akx[s][q] = (short)f2bf(Bw_T[k * NX + r]);
      float du = 0.f;
      if (wv == 1 && r < NU) du = Duw_T[k * NU + r];
      Aku[s][q] = (short)f2bf(du);
    }
  }
  f4v lsv;
#pragma unroll
  for (int i = 0; i < 4; ++i) lsv[i] = (h >= 2) ? log_stds[4 * (h - 2) + i] : 0.f;

  f4v xr;
#pragma unroll
  for (int i = 0; i < 4; ++i) xr[i] = x0[grow * NX + 4 * h + i];

  {  // zero w buf0 (cold-start w0)
    uint4 z; z.x = z.y = z.z = z.w = 0u;
    ((uint4*)wlds)[tid] = z;
  }

  const float* orow = obs + grow * T_SZ * NY;
  bf8v By0, By1;
  {
    float yf[8];
#pragma unroll
    for (int q = 0; q < 8; ++q) yf[q] = orow[8 * h + q];
#pragma unroll
    for (int q = 0; q < 8; ++q) {
      unsigned short hi = f2bf(yf[q]);
      By0[q] = (short)hi;
      By1[q] = (short)f2bf(yf[q] - bf2f(hi));
    }
  }
  wave_barrier();  // wlds zeros visible

  // x (D-layout f4v: lane holds x[4h+i][row r]) -> B-frag (hi16|lo16) via bpermute
  auto x_to_bfrag = [&](f4v v) -> bf8v {
    unsigned short hb0 = f2bf(v[0]), hb1 = f2bf(v[1]), hb2 = f2bf(v[2]), hb3 = f2bf(v[3]);
    unsigned hiP0 = (unsigned)hb0 | ((unsigned)hb1 << 16);
    unsigned hiP1 = (unsigned)hb2 | ((unsigned)hb3 << 16);
    unsigned loP0 = (unsigned)f2bf(v[0] - bf2f(hb0)) | ((unsigned)f2bf(v[1] - bf2f(hb1)) << 16);
    unsigned loP1 = (unsigned)f2bf(v[2] - bf2f(hb2)) | ((unsigned)f2bf(v[3] - bf2f(hb3)) << 16);
    int a0 = __builtin_amdgcn_ds_bpermute(ti0, (int)hiP0);
    int a1 = __builtin_amdgcn_ds_bpermute(ti0, (int)hiP1);
    int a2 = __builtin_amdgcn_ds_bpermute(ti1, (int)hiP0);
    int a3 = __builtin_amdgcn_ds_bpermute(ti1, (int)hiP1);
    int b0 = __builtin_amdgcn_ds_bpermute(ti0, (int)loP0);
    int b1_ = __builtin_amdgcn_ds_bpermute(ti0, (int)loP1);
    int b2_ = __builtin_amdgcn_ds_bpermute(ti1, (int)loP0);
    int b3_ = __builtin_amdgcn_ds_bpermute(ti1, (int)loP1);
    int4 d;
    d.x = hi_sel ? a0 : b0;
    d.y = hi_sel ? a1 : b1_;
    d.z = hi_sel ? a2 : b2_;
    d.w = hi_sel ? a3 : b3_;
    return __builtin_bit_cast(bf8v, d);
  };

  f4v cb0, cb1, cbias0, cbias1, acc;
  bf8v bxc;  // current stage's x as B-frag
  {
    f4v z4 = {0.f, 0.f, 0.f, 0.f};
    cb0 = MFMA16(Ady[0], By0, z4); cb0 = MFMA16(Ady[0], By1, cb0);
    cb1 = MFMA16(Ady[1], By0, z4); cb1 = MFMA16(Ady[1], By1, cb1);
    bxc = x_to_bfrag(xr);
    cbias0 = MFMA16(Acv[0], bxc, cb0);
    cbias1 = MFMA16(Acv[1], bxc, cb1);
  }

  int co = 0;
  bf8v of8 = {};  // own w-slice (B-frag slot 0); w0 = 0

  auto solve_iter = [&]() {
    const char* wb = wlds + co;
    bf8v b1 = *(const bf8v*)(wb + rbase + ro1);
    bf8v b2 = *(const bf8v*)(wb + rbase + ro2);
    bf8v b3 = *(const bf8v*)(wb + rbase + ro3);
    f4v c0 = MFMA16(Adw[0][0], of8, cbias0);   // own slot first: hides LDS latency
    f4v c1 = MFMA16(Adw[1][0], of8, cbias1);
    c0 = MFMA16(Adw[0][1], b1, c0);  c1 = MFMA16(Adw[1][1], b1, c1);
    c0 = MFMA16(Adw[0][2], b2, c0);  c1 = MFMA16(Adw[1][2], b2, c1);
    c0 = MFMA16(Adw[0][3], b3, c0);  c1 = MFMA16(Adw[1][3], b3, c1);
    bf8v o;
    o[0] = tanh_bf(c0[0]); o[1] = tanh_bf(c0[1]); o[2] = tanh_bf(c0[2]); o[3] = tanh_bf(c0[3]);
    o[4] = tanh_bf(c1[0]); o[5] = tanh_bf(c1[1]); o[6] = tanh_bf(c1[2]); o[7] = tanh_bf(c1[3]);
    of8 = o;
    *(bf8v*)(wlds + (co ^ 4096) + rbase + ro0) = o;
    wave_barrier();
    co ^= 4096;
  };

  for (int it = 0; it < NCOLD - 4; ++it) solve_iter();  // 26; loop adds 4 per stage-1

  float yn[8];

  // Fused boundary: kchain + (u) + x-update + bias + FIRST solve iter of next stage.
  // mode: 1 = S1->S2 (u out, acc=kv, xs=x+.5dt k), 2 = S2->S3, 3 = S3->S4 (xs=x+dt k),
  //       4 = S4->S1' (xr+=dt/6(acc+kv), y swap, next-step bias)
  auto fusedB = [&](int mode, int t) {
    const char* wb = wlds + co;
    bf8v b1 = *(const bf8v*)(wb + rbase + ro1);
    bf8v b2 = *(const bf8v*)(wb + rbase + ro2);
    bf8v b3 = *(const bf8v*)(wb + rbase + ro3);
    f4v z4 = {0.f, 0.f, 0.f, 0.f};
    // k-chain: register-only MFMAs first (fill LDS-latency shadow)
    f4v kv = MFMA16(Ax, bxc, z4);
    kv = MFMA16(Akx[0], of8, kv);
    kv = MFMA16(Ayx, By0, kv);  kv = MFMA16(Ayx, By1, kv);
    kv = MFMA16(Akx[1], b1, kv); kv = MFMA16(Akx[2], b2, kv); kv = MFMA16(Akx[3], b3, kv);
    if (mode == 1 && wv == 1) {  // action output (fire-and-forget store)
      f4v cu = MFMA16(Au, bxc, z4);
      cu = MFMA16(Aku[0], of8, cu);
      cu = MFMA16(Ayu, By0, cu);  cu = MFMA16(Ayu, By1, cu);
      cu = MFMA16(Aku[1], b1, cu); cu = MFMA16(Aku[2], b2, cu); cu = MFMA16(Aku[3], b3, cu);
      f4v sv;
#pragma unroll
      for (int i = 0; i < 4; ++i) sv[i] = (h < 2) ? cu[i] : lsv[i];
      *(f4v*)(out + (grow * T_SZ + t) * 16 + 4 * h) = sv;
    }
    f4v xs;
    if (mode == 1) {
      acc = kv;
#pragma unroll
      for (int i = 0; i < 4; ++i) xs[i] = xr[i] + (0.5f * DT_F) * kv[i];
    } else if (mode == 2) {
#pragma unroll
      for (int i = 0; i < 4; ++i) { acc[i] += 2.f * kv[i]; xs[i] = xr[i] + (0.5f * DT_F) * kv[i]; }
    } else if (mode == 3) {
#pragma unroll
      for (int i = 0; i < 4; ++i) { acc[i] += 2.f * kv[i]; xs[i] = xr[i] + DT_F * kv[i]; }
    } else {
#pragma unroll
      for (int i = 0; i < 4; ++i) xr[i] += (DT_F / 6.f) * (acc[i] + kv[i]);
      xs = xr;
    }
    bf8v bxn = x_to_bfrag(xs);
    if (mode == 4) {  // swap in prefetched y, recompute y-bias
#pragma unroll
      for (int q = 0; q < 8; ++q) {
        unsigned short hi = f2bf(yn[q]);
        By0[q] = (short)hi;
        By1[q] = (short)f2bf(yn[q] - bf2f(hi));
      }
      cb0 = MFMA16(Ady[0], By0, z4); cb0 = MFMA16(Ady[0], By1, cb0);
      cb1 = MFMA16(Ady[1], By0, z4); cb1 = MFMA16(Ady[1], By1, cb1);
    }
    cbias0 = MFMA16(Acv[0], bxn, cb0);
    cbias1 = MFMA16(Acv[1], bxn, cb1);
    // first solve iteration of the next stage: w-part from zero (b-frags already held)
    f4v d0 = MFMA16(Adw[0][0], of8, z4);
    d0 = MFMA16(Adw[0][1], b1, d0); d0 = MFMA16(Adw[0][2], b2, d0); d0 = MFMA16(Adw[0][3], b3, d0);
    f4v d1 = MFMA16(Adw[1][0], of8, z4);
    d1 = MFMA16(Adw[1][1], b1, d1); d1 = MFMA16(Adw[1][2], b2, d1); d1 = MFMA16(Adw[1][3], b3, d1);
    f4v c0, c1;
#pragma unroll
    for (int i = 0; i < 4; ++i) { c0[i] = d0[i] + cbias0[i]; c1[i] = d1[i] + cbias1[i]; }
    bf8v o;
    o[0] = tanh_bf(c0[0]); o[1] = tanh_bf(c0[1]); o[2] = tanh_bf(c0[2]); o[3] = tanh_bf(c0[3]);
    o[4] = tanh_bf(c1[0]); o[5] = tanh_bf(c1[1]); o[6] = tanh_bf(c1[2]); o[7] = tanh_bf(c1[3]);
    of8 = o;
    *(bf8v*)(wlds + (co ^ 4096) + rbase + ro0) = o;
    wave_barrier();
    co ^= 4096;
    bxc = bxn;
  };

  for (int t = 0; t < T_SZ; ++t) {
    // stage 1 (remaining 4 iters; first was fused into prev B4 / prologue)
    for (int i = 0; i < 4; ++i) solve_iter();
    fusedB(1, t);
    {  // prefetch next y early; consumed at fusedB(4) ~12 barrier-units later
      const long tn = (t + 1 < T_SZ) ? (t + 1) : t;
#pragma unroll
      for (int q = 0; q < 8; ++q) yn[q] = orow[tn * NY + 8 * h + q];
    }
    for (int i = 0; i < 4; ++i) solve_iter();
    fusedB(2, t);
    for (int i = 0; i < 4; ++i) solve_iter();
    fusedB(3, t);
    for (int i = 0; i < 4; ++i) solve_iter();
    fusedB(4, t);
  }
}

extern "C" void kernel_launch(void* const* d_in, const int* in_sizes, int n_in,
                              void* d_out, int out_size, void* d_ws, size_t ws_size,
                              hipStream_t stream) {
  (void)in_sizes; (void)n_in; (void)out_size; (void)d_ws; (void)ws_size;
  rinn_kernel<<<64, 256, 0, stream>>>(
      (const float*)d_in[0], (const float*)d_in[1], (const float*)d_in[2],
      (const float*)d_in[3], (const float*)d_in[4], (const float*)d_in[5],
      (const float*)d_in[6], (const float*)d_in[7], (const float*)d_in[8],
      (const float*)d_in[9], (const float*)d_in[10], (const float*)d_in[11],
      (float*)d_out);
}